// Round 9
// baseline (366.848 us; speedup 1.0000x reference)
//
#include <hip/hip_runtime.h>
#include <cstdint>

typedef __bf16 bf16x8 __attribute__((ext_vector_type(8)));
typedef float f32x4 __attribute__((ext_vector_type(4)));

#define DIM 512
#define TSEQ 4096

__device__ __forceinline__ ushort f2bf(float x) {
  uint32_t u = __float_as_uint(x);
  u += 0x7fffu + ((u >> 16) & 1u);
  return (ushort)(u >> 16);
}
__device__ __forceinline__ float bf2f(ushort u) {
  return __uint_as_float(((uint32_t)u) << 16);
}

// ---------------- gates: gk, gv, gb1, gb2 (64 blocks; block 0 also does elementwise)
__global__ __launch_bounds__(512)
void gates_kernel(const float* __restrict__ qv, const float* __restrict__ kv,
                  const float* __restrict__ vvec,
                  const float* __restrict__ Ws, const float* __restrict__ bs,
                  const float* __restrict__ Wt, const float* __restrict__ bt,
                  const float* __restrict__ gamma, const float* __restrict__ beta,
                  float* __restrict__ gk, float* __restrict__ gv,
                  float* __restrict__ gb1, float* __restrict__ gb2) {
  __shared__ float vv[DIM];
  const int t = threadIdx.x;
  const int lane = t & 63, w = t >> 6;
  vv[t] = 1.f / (1.f + __expf(-vvec[t]));
  if (blockIdx.x == 0) {
    const float SC = 0.044194173824159216f;  // 1/sqrt(512)
    float gqv = 1.f / (1.f + __expf(-qv[t]));
    gk[t] = 1.f / (1.f + __expf(-kv[t]));
    gb1[t] = gamma[t] * gqv * SC;
    gb2[t] = beta[t] * gqv * SC;
  }
  __syncthreads();
  const int d = blockIdx.x * 8 + w;
  const float* wsr = Ws + (size_t)d * DIM + lane * 8;
  const float* wtr = Wt + (size_t)d * DIM + lane * 8;
  float4 v0 = *(const float4*)(&vv[lane * 8]);
  float4 v1 = *(const float4*)(&vv[lane * 8 + 4]);
  float4 s0 = *(const float4*)wsr, s1 = *(const float4*)(wsr + 4);
  float4 t0 = *(const float4*)wtr, t1 = *(const float4*)(wtr + 4);
  float as = v0.x*s0.x + v0.y*s0.y + v0.z*s0.z + v0.w*s0.w
           + v1.x*s1.x + v1.y*s1.y + v1.z*s1.z + v1.w*s1.w;
  float at = v0.x*t0.x + v0.y*t0.y + v0.z*t0.z + v0.w*t0.w
           + v1.x*t1.x + v1.y*t1.y + v1.z*t1.z + v1.w*t1.w;
  #pragma unroll
  for (int off = 1; off < 64; off <<= 1) {
    as += __shfl_xor(as, off, 64);
    at += __shfl_xor(at, off, 64);
  }
  if (lane == 0) {
    float sg = 1.f / (1.f + __expf(-(as + bs[d])));
    float th = tanhf(at + bt[d]);
    gv[d] = sg * th;
  }
}

// ---------------- Wq f32 -> bf16
__global__ __launch_bounds__(256)
void wconv_kernel(const float* __restrict__ W, ushort* __restrict__ Wb) {
  int i = blockIdx.x * 256 + threadIdx.x;
  float4 v = ((const float4*)W)[i];
  ushort4 o = { f2bf(v.x), f2bf(v.y), f2bf(v.z), f2bf(v.w) };
  ((ushort4*)Wb)[i] = o;
}

// ---------------- fused qGEMM (A @ Wq^T + bq) + LayerNorm + gate + scale -> bf16 qb
__global__ __launch_bounds__(256, 2)
void qgemmln_kernel(const float* __restrict__ A, const ushort* __restrict__ Wb,
                    const float* __restrict__ bq,
                    const float* __restrict__ gb1, const float* __restrict__ gb2,
                    ushort* __restrict__ qout) {
  __shared__ ushort As[32][40];
  __shared__ float rws[4][32], rws2[4][32];
  const int t = threadIdx.x;
  const int lane = t & 63, w = t >> 6;
  const int r16 = lane & 15, kb8 = lane >> 4;
  const int rowbase = blockIdx.x * 32;
  f32x4 acc[2][8];
  #pragma unroll
  for (int m = 0; m < 2; ++m)
    #pragma unroll
    for (int n = 0; n < 8; ++n) acc[m][n] = (f32x4)0.f;

  for (int kb = 0; kb < 16; ++kb) {
    const int k0 = kb * 32;
    __syncthreads();
    {
      int ar = t >> 3, ac = (t & 7) * 4;
      float4 a = *(const float4*)(A + (size_t)(rowbase + ar) * DIM + k0 + ac);
      ushort4 u = { f2bf(a.x), f2bf(a.y), f2bf(a.z), f2bf(a.w) };
      *(ushort4*)&As[ar][ac] = u;
    }
    __syncthreads();
    bf16x8 a0 = *(const bf16x8*)&As[r16][kb8 * 8];
    bf16x8 a1 = *(const bf16x8*)&As[16 + r16][kb8 * 8];
    #pragma unroll
    for (int n = 0; n < 8; ++n) {
      bf16x8 bb = *(const bf16x8*)(Wb + (size_t)(w * 128 + n * 16 + r16) * DIM + k0 + kb8 * 8);
      acc[0][n] = __builtin_amdgcn_mfma_f32_16x16x32_bf16(a0, bb, acc[0][n], 0, 0, 0);
      acc[1][n] = __builtin_amdgcn_mfma_f32_16x16x32_bf16(a1, bb, acc[1][n], 0, 0, 0);
    }
  }
  float s_[2][4], ss_[2][4];
  #pragma unroll
  for (int m = 0; m < 2; ++m)
    #pragma unroll
    for (int r = 0; r < 4; ++r) { s_[m][r] = 0.f; ss_[m][r] = 0.f; }
  #pragma unroll
  for (int n = 0; n < 8; ++n) {
    float bqv = bq[w * 128 + n * 16 + r16];
    #pragma unroll
    for (int m = 0; m < 2; ++m)
      #pragma unroll
      for (int r = 0; r < 4; ++r) {
        float v = acc[m][n][r] + bqv;
        acc[m][n][r] = v;
        s_[m][r] += v;
        ss_[m][r] += v * v;
      }
  }
  #pragma unroll
  for (int m = 0; m < 2; ++m)
    #pragma unroll
    for (int r = 0; r < 4; ++r)
      #pragma unroll
      for (int off = 1; off < 16; off <<= 1) {
        s_[m][r]  += __shfl_xor(s_[m][r], off, 64);
        ss_[m][r] += __shfl_xor(ss_[m][r], off, 64);
      }
  if (r16 == 0) {
    #pragma unroll
    for (int m = 0; m < 2; ++m)
      #pragma unroll
      for (int r = 0; r < 4; ++r) {
        int row = m * 16 + kb8 * 4 + r;
        rws[w][row]  = s_[m][r];
        rws2[w][row] = ss_[m][r];
      }
  }
  __syncthreads();
  float mu_[2][4], rs_[2][4];
  #pragma unroll
  for (int m = 0; m < 2; ++m)
    #pragma unroll
    for (int r = 0; r < 4; ++r) {
      int row = m * 16 + kb8 * 4 + r;
      float s = rws[0][row] + rws[1][row] + rws[2][row] + rws[3][row];
      float q = rws2[0][row] + rws2[1][row] + rws2[2][row] + rws2[3][row];
      float mu = s * (1.f / DIM);
      float var = q * (1.f / DIM) - mu * mu;
      mu_[m][r] = mu;
      rs_[m][r] = rsqrtf(var + 1e-5f);
    }
  #pragma unroll
  for (int n = 0; n < 8; ++n) {
    int col = w * 128 + n * 16 + r16;
    float g1 = gb1[col], g2 = gb2[col];
    #pragma unroll
    for (int m = 0; m < 2; ++m)
      #pragma unroll
      for (int r = 0; r < 4; ++r) {
        int row = rowbase + m * 16 + kb8 * 4 + r;
        float o = (acc[m][n][r] - mu_[m][r]) * rs_[m][r] * g1 + g2;
        qout[(size_t)row * DIM + col] = f2bf(o);
      }
  }
}

// ---------------- fused: kb = bf16(value*gk) row-major; vT[b][d][t] = bf16(value*gv)
__global__ __launch_bounds__(256)
void vkprep_kernel(const float* __restrict__ value, const float* __restrict__ gk,
                   const float* __restrict__ gv,
                   ushort* __restrict__ kbuf, ushort* __restrict__ vT) {
  __shared__ ushort tile[64][73];
  const int t = threadIdx.x;
  const int s0 = blockIdx.x * 64, d0 = blockIdx.y * 64;
  const size_t boff = (size_t)blockIdx.z * TSEQ * DIM;
  #pragma unroll
  for (int rep = 0; rep < 4; ++rep) {
    int f = rep * 1024 + t * 4;
    int sr = f >> 6, dc = f & 63;
    float4 v = *(const float4*)(value + boff + (size_t)(s0 + sr) * DIM + d0 + dc);
    float4 g = *(const float4*)(gv + d0 + dc);
    float4 gg = *(const float4*)(gk + d0 + dc);
    tile[sr][dc]     = f2bf(v.x * g.x);
    tile[sr][dc + 1] = f2bf(v.y * g.y);
    tile[sr][dc + 2] = f2bf(v.z * g.z);
    tile[sr][dc + 3] = f2bf(v.w * g.w);
    ushort4 ko = { f2bf(v.x*gg.x), f2bf(v.y*gg.y), f2bf(v.z*gg.z), f2bf(v.w*gg.w) };
    *(ushort4*)(kbuf + boff + (size_t)(s0 + sr) * DIM + d0 + dc) = ko;
  }
  __syncthreads();
  const int d = t >> 2, sc0 = (t & 3) * 16;
  __align__(16) ushort tmp[16];
  #pragma unroll
  for (int j = 0; j < 16; ++j) tmp[j] = tile[sc0 + j][d];
  ushort* dst = vT + (size_t)blockIdx.z * DIM * TSEQ + (size_t)(d0 + d) * TSEQ + s0 + sc0;
  ((uint4*)dst)[0] = *(const uint4*)&tmp[0];
  ((uint4*)dst)[1] = *(const uint4*)&tmp[8];
}

// ---------------- causal flash attention, QB=32, KVB=64, 4 waves/block, 2 blocks/CU
// 512 jobs: pair (p, 127-p) per batch, split 32/33 kv-visits across two blocks.
// Fixed-max softmax; swapped QK^T (reg index runs along kv -> b128 Sp stores).
__global__ __launch_bounds__(256)
void attn7_kernel(const ushort* __restrict__ qb, const ushort* __restrict__ kb,
                  const ushort* __restrict__ vT, float* __restrict__ out,
                  ushort* __restrict__ pO, float* __restrict__ stats) {
  __shared__ __align__(16) float Sp[4][32][68];   // 34.8KB
  __shared__ __align__(16) ushort P[32][72];      // 4.6KB
  __shared__ float lrow[32];

  const int t = threadIdx.x;
  const int lane = t & 63;
  const int dcQ = t >> 6;          // wave = D chunk (128 wide)
  const int r16 = lane & 15;
  const int kb8 = lane >> 4;

  const int bid = blockIdx.x;
  const int job = ((bid & 7) << 6) | (bid >> 3);   // 512 = 8 XCDs * 64
  const int pid = job >> 1;        // 0..255 : (b, p)
  const int half = job & 1;
  const int b = pid >> 6;
  const int p = pid & 63;

  const size_t boff  = (size_t)b * TSEQ * DIM;
  const size_t vboff = (size_t)b * DIM * TSEQ;
  const int nk_small = (p >> 1) + 1;               // kv tiles for qt=p
  const int nk_large = ((127 - p) >> 1) + 1;       // kv tiles for qt=127-p
  const int prefix = 32 - nk_small;                // large-tile prefix handled by half 0

  for (int ji = 0; ji < 2; ++ji) {
    int qt, kt0, kt1, mode, cid;
    if (half) {
      if (ji) break;
      qt = 127 - p; kt0 = prefix; kt1 = nk_large; mode = 1; cid = pid*2 + 1;
    } else if (ji == 0) {
      qt = p; kt0 = 0; kt1 = nk_small; mode = 0; cid = 0;
    } else {
      qt = 127 - p; kt0 = 0; kt1 = prefix; mode = 1; cid = pid*2;
    }
    const int qbase = qt * 32;

    __syncthreads();   // previous job epilogue done before lrow re-init
    if (t < 32) lrow[t] = 0.f;

    bf16x8 aQ[2][4];
    #pragma unroll
    for (int m = 0; m < 2; ++m)
      #pragma unroll
      for (int c = 0; c < 4; ++c)
        aQ[m][c] = *(const bf16x8*)(qb + boff + (size_t)(qbase + m*16 + r16) * DIM
                                    + dcQ*128 + c*32 + kb8*8);
    f32x4 accO[2][8];
    #pragma unroll
    for (int m = 0; m < 2; ++m)
      #pragma unroll
      for (int n = 0; n < 8; ++n) accO[m][n] = (f32x4)0.f;

    // --- prologue: QK^T(kt0)
    if (kt0 < kt1) {
      const int kbase = kt0 * 64;
      f32x4 accS[2][4];
      #pragma unroll
      for (int m = 0; m < 2; ++m)
        #pragma unroll
        for (int n = 0; n < 4; ++n) accS[m][n] = (f32x4)0.f;
      #pragma unroll
      for (int c = 0; c < 4; ++c) {
        bf16x8 bK[4];
        #pragma unroll
        for (int n = 0; n < 4; ++n)
          bK[n] = *(const bf16x8*)(kb + boff + (size_t)(kbase + n*16 + r16) * DIM
                                   + dcQ*128 + c*32 + kb8*8);
        #pragma unroll
        for (int m = 0; m < 2; ++m)
          #pragma unroll
          for (int n = 0; n < 4; ++n)
            accS[m][n] = __builtin_amdgcn_mfma_f32_16x16x32_bf16(bK[n], aQ[m][c], accS[m][n], 0, 0, 0);
      }
      #pragma unroll
      for (int m = 0; m < 2; ++m)
        #pragma unroll
        for (int n = 0; n < 4; ++n)
          *(f32x4*)&Sp[dcQ][m*16 + r16][n*16 + kb8*4] = accS[m][n];
    }
    __syncthreads();

    for (int kt = kt0; kt < kt1; ++kt) {
      const int kbase = kt * 64;
      const bool havek = (kt + 1 < kt1);

      // --- phase A: fixed-max softmax (p = exp(S), no rescale)
      {
        const int row = t >> 3, c0 = (t & 7) * 8;
        float sv[8];
        #pragma unroll
        for (int j = 0; j < 8; ++j) sv[j] = 0.f;
        #pragma unroll
        for (int ch = 0; ch < 4; ++ch) {
          float4 u0 = *(const float4*)&Sp[ch][row][c0];
          float4 u1 = *(const float4*)&Sp[ch][row][c0 + 4];
          sv[0] += u0.x; sv[1] += u0.y; sv[2] += u0.z; sv[3] += u0.w;
          sv[4] += u1.x; sv[5] += u1.y; sv[6] += u1.z; sv[7] += u1.w;
        }
        const int qg = qbase + row;
        float ps = 0.f;
        #pragma unroll
        for (int j = 0; j < 8; ++j) {
          sv[j] = (kbase + c0 + j > qg) ? 0.f : __expf(sv[j]);
          ps += sv[j];
        }
        ps += __shfl_xor(ps, 1, 64);
        ps += __shfl_xor(ps, 2, 64);
        ps += __shfl_xor(ps, 4, 64);
        ushort4 p0 = { f2bf(sv[0]), f2bf(sv[1]), f2bf(sv[2]), f2bf(sv[3]) };
        ushort4 p1 = { f2bf(sv[4]), f2bf(sv[5]), f2bf(sv[6]), f2bf(sv[7]) };
        *(ushort4*)&P[row][c0] = p0;
        *(ushort4*)&P[row][c0 + 4] = p1;
        if ((t & 7) == 0) lrow[row] += ps;
      }
      __syncthreads();

      // --- phase B: PV(kt) + QK^T(kt+1)
      __builtin_amdgcn_s_setprio(1);
      #pragma unroll
      for (int c = 0; c < 2; ++c) {
        bf16x8 aP[2];
        aP[0] = *(const bf16x8*)&P[r16][c*32 + kb8*8];
        aP[1] = *(const bf16x8*)&P[16 + r16][c*32 + kb8*8];
        #pragma unroll
        for (int n = 0; n < 8; ++n) {
          bf16x8 bV = *(const bf16x8*)(vT + vboff + (size_t)(dcQ*128 + n*16 + r16) * TSEQ
                                       + kbase + c*32 + kb8*8);
          accO[0][n] = __builtin_amdgcn_mfma_f32_16x16x32_bf16(aP[0], bV, accO[0][n], 0, 0, 0);
          accO[1][n] = __builtin_amdgcn_mfma_f32_16x16x32_bf16(aP[1], bV, accO[1][n], 0, 0, 0);
        }
      }
      if (havek) {
        const int kb2 = (kt + 1) * 64;
        f32x4 accS[2][4];
        #pragma unroll
        for (int m = 0; m < 2; ++m)
          #pragma unroll
          for (int n = 0; n < 4; ++n) accS[m][n] = (f32x4)0.f;
        #pragma unroll
        for (int c = 0; c < 4; ++c) {
          bf16x8 bK[4];
          #pragma unroll
          for (int n = 0; n < 4; ++n)
            bK[n] = *(const bf16x8*)(kb + boff + (size_t)(kb2 + n*16 + r16) * DIM
                                     + dcQ*128 + c*32 + kb8*8);
          #pragma unroll
          for (int m = 0; m < 2; ++m)
            #pragma unroll
            for (int n = 0; n < 4; ++n)
              accS[m][n] = __builtin_amdgcn_mfma_f32_16x16x32_bf16(bK[n], aQ[m][c], accS[m][n], 0, 0, 0);
        }
        #pragma unroll
        for (int m = 0; m < 2; ++m)
          #pragma unroll
          for (int n = 0; n < 4; ++n)
            *(f32x4*)&Sp[dcQ][m*16 + r16][n*16 + kb8*4] = accS[m][n];
      }
      __builtin_amdgcn_s_setprio(0);
      __syncthreads();
    }

    // --- epilogue
    if (mode == 0) {
      #pragma unroll
      for (int m = 0; m < 2; ++m)
        #pragma unroll
        for (int r = 0; r < 4; ++r) {
          int row = m*16 + kb8*4 + r;
          float inv = 1.f / lrow[row];
          float* dst = out + boff + (size_t)(qbase + row) * DIM + dcQ*128 + r16;
          #pragma unroll
          for (int n = 0; n < 8; ++n) dst[n*16] = accO[m][n][r] * inv;
        }
    } else {
      ushort* po = pO + (size_t)cid * (32 * DIM);
      #pragma unroll
      for (int m = 0; m < 2; ++m)
        #pragma unroll
        for (int r = 0; r < 4; ++r) {
          int row = m*16 + kb8*4 + r;
          ushort* dst = po + (size_t)row * DIM + dcQ*128 + r16;
          #pragma unroll
          for (int n = 0; n < 8; ++n) dst[n*16] = f2bf(accO[m][n][r]);
        }
      if (t < 32) stats[(size_t)cid*32 + t] = lrow[t];
    }
  }
}

// ---------------- combine the two partials of each large q-tile (weights = 1)
__global__ __launch_bounds__(256)
void comb_kernel(const ushort* __restrict__ pO, const float* __restrict__ stats,
                 float* __restrict__ out) {
  const int g = blockIdx.x;       // 0..255: (b, p)
  const int rb = blockIdx.y;      // 0..7
  const int t = threadIdx.x;
  const int b = g >> 6, p = g & 63, qt = 127 - p;
  const int row = rb * 4 + (t >> 6);
  const int col = (t & 63) * 8;
  float l0 = stats[(size_t)(g*2 + 0)*32 + row];
  float l1 = stats[(size_t)(g*2 + 1)*32 + row];
  float inv = 1.f / (l0 + l1);
  const ushort* pa = pO + ((size_t)(g*2 + 0) * 32 + row) * DIM + col;
  const ushort* pb = pO + ((size_t)(g*2 + 1) * 32 + row) * DIM + col;
  ushort4 a0 = ((const ushort4*)pa)[0], a1 = ((const ushort4*)pa)[1];
  ushort4 b0 = ((const ushort4*)pb)[0], b1 = ((const ushort4*)pb)[1];
  float* dst = out + ((size_t)b * TSEQ + (size_t)qt * 32 + row) * DIM + col;
  float4 o0 = { (bf2f(a0.x) + bf2f(b0.x)) * inv, (bf2f(a0.y) + bf2f(b0.y)) * inv,
                (bf2f(a0.z) + bf2f(b0.z)) * inv, (bf2f(a0.w) + bf2f(b0.w)) * inv };
  float4 o1 = { (bf2f(a1.x) + bf2f(b1.x)) * inv, (bf2f(a1.y) + bf2f(b1.y)) * inv,
                (bf2f(a1.z) + bf2f(b1.z)) * inv, (bf2f(a1.w) + bf2f(b1.w)) * inv };
  ((float4*)dst)[0] = o0;
  ((float4*)dst)[1] = o1;
}

extern "C" void kernel_launch(void* const* d_in, const int* in_sizes, int n_in,
                              void* d_out, int out_size, void* d_ws, size_t ws_size,
                              hipStream_t stream) {
  const float* query = (const float*)d_in[0];
  const float* value = (const float*)d_in[1];
  const float* qv    = (const float*)d_in[2];
  const float* kv    = (const float*)d_in[3];
  const float* vvec  = (const float*)d_in[4];
  const float* Wq    = (const float*)d_in[5];
  const float* bq    = (const float*)d_in[6];
  const float* gam   = (const float*)d_in[7];
  const float* bet   = (const float*)d_in[8];
  const float* Ws    = (const float*)d_in[9];
  const float* bs    = (const float*)d_in[10];
  const float* Wt    = (const float*)d_in[11];
  const float* bt    = (const float*)d_in[12];
  float* out = (float*)d_out;

  char* ws = (char*)d_ws;
  float*  gk    = (float*)(ws);                    // 2KB
  float*  gv    = (float*)(ws + 2048);             // 2KB
  float*  gb1   = (float*)(ws + 4096);             // 2KB
  float*  gb2   = (float*)(ws + 6144);             // 2KB
  ushort* Wb    = (ushort*)(ws + 8192);            // 512KB
  float*  stats = (float*)(ws + 532480);           // 512*32*4 = 64KB
  ushort* pO    = (ushort*)(ws + 663552);          // 512*32*512*2 = 16MB
  ushort* qb    = (ushort*)(ws + 17440768);        // 16MB
  ushort* kb    = (ushort*)(ws + 34217984);        // 16MB
  ushort* vT    = (ushort*)(ws + 50995200);        // 16MB (end ~67MB)

  gates_kernel<<<64, 512, 0, stream>>>(qv, kv, vvec, Ws, bs, Wt, bt, gam, bet,
                                       gk, gv, gb1, gb2);
  wconv_kernel<<<256, 256, 0, stream>>>(Wq, Wb);
  qgemmln_kernel<<<512, 256, 0, stream>>>(query, Wb, bq, gb1, gb2, qb);
  vkprep_kernel<<<dim3(64, 8, 4), 256, 0, stream>>>(value, gk, gv, kb, vT);
  attn7_kernel<<<512, 256, 0, stream>>>(qb, kb, vT, out, pO, stats);
  comb_kernel<<<dim3(256, 8), 256, 0, stream>>>(pO, stats, out);
}

// Round 10
// 333.814 us; speedup vs baseline: 1.0990x; 1.0990x over previous
//
#include <hip/hip_runtime.h>
#include <cstdint>

typedef __bf16 bf16x8 __attribute__((ext_vector_type(8)));
typedef float f32x4 __attribute__((ext_vector_type(4)));

#define DIM 512
#define TSEQ 4096

__device__ __forceinline__ ushort f2bf(float x) {
  uint32_t u = __float_as_uint(x);
  u += 0x7fffu + ((u >> 16) & 1u);
  return (ushort)(u >> 16);
}

// ---------------- gates: gk, gv, gb1, gb2 (64 blocks; block 0 also does elementwise)
__global__ __launch_bounds__(512)
void gates_kernel(const float* __restrict__ qv, const float* __restrict__ kv,
                  const float* __restrict__ vvec,
                  const float* __restrict__ Ws, const float* __restrict__ bs,
                  const float* __restrict__ Wt, const float* __restrict__ bt,
                  const float* __restrict__ gamma, const float* __restrict__ beta,
                  float* __restrict__ gk, float* __restrict__ gv,
                  float* __restrict__ gb1, float* __restrict__ gb2) {
  __shared__ float vv[DIM];
  const int t = threadIdx.x;
  const int lane = t & 63, w = t >> 6;
  vv[t] = 1.f / (1.f + __expf(-vvec[t]));
  if (blockIdx.x == 0) {
    const float SC = 0.044194173824159216f;  // 1/sqrt(512)
    float gqv = 1.f / (1.f + __expf(-qv[t]));
    gk[t] = 1.f / (1.f + __expf(-kv[t]));
    gb1[t] = gamma[t] * gqv * SC;
    gb2[t] = beta[t] * gqv * SC;
  }
  __syncthreads();
  const int d = blockIdx.x * 8 + w;
  const float* wsr = Ws + (size_t)d * DIM + lane * 8;
  const float* wtr = Wt + (size_t)d * DIM + lane * 8;
  float4 v0 = *(const float4*)(&vv[lane * 8]);
  float4 v1 = *(const float4*)(&vv[lane * 8 + 4]);
  float4 s0 = *(const float4*)wsr, s1 = *(const float4*)(wsr + 4);
  float4 t0 = *(const float4*)wtr, t1 = *(const float4*)(wtr + 4);
  float as = v0.x*s0.x + v0.y*s0.y + v0.z*s0.z + v0.w*s0.w
           + v1.x*s1.x + v1.y*s1.y + v1.z*s1.z + v1.w*s1.w;
  float at = v0.x*t0.x + v0.y*t0.y + v0.z*t0.z + v0.w*t0.w
           + v1.x*t1.x + v1.y*t1.y + v1.z*t1.z + v1.w*t1.w;
  #pragma unroll
  for (int off = 1; off < 64; off <<= 1) {
    as += __shfl_xor(as, off, 64);
    at += __shfl_xor(at, off, 64);
  }
  if (lane == 0) {
    float sg = 1.f / (1.f + __expf(-(as + bs[d])));
    float th = tanhf(at + bt[d]);
    gv[d] = sg * th;
  }
}

// ---------------- Wq f32 -> bf16
__global__ __launch_bounds__(256)
void wconv_kernel(const float* __restrict__ W, ushort* __restrict__ Wb) {
  int i = blockIdx.x * 256 + threadIdx.x;
  float4 v = ((const float4*)W)[i];
  ushort4 o = { f2bf(v.x), f2bf(v.y), f2bf(v.z), f2bf(v.w) };
  ((ushort4*)Wb)[i] = o;
}

// ---------------- fused qGEMM (A @ Wq^T + bq) + LayerNorm + gate + scale -> bf16 qb
__global__ __launch_bounds__(256, 2)
void qgemmln_kernel(const float* __restrict__ A, const ushort* __restrict__ Wb,
                    const float* __restrict__ bq,
                    const float* __restrict__ gb1, const float* __restrict__ gb2,
                    ushort* __restrict__ qout) {
  __shared__ ushort As[32][40];
  __shared__ float rws[4][32], rws2[4][32];
  const int t = threadIdx.x;
  const int lane = t & 63, w = t >> 6;
  const int r16 = lane & 15, kb8 = lane >> 4;
  const int rowbase = blockIdx.x * 32;
  f32x4 acc[2][8];
  #pragma unroll
  for (int m = 0; m < 2; ++m)
    #pragma unroll
    for (int n = 0; n < 8; ++n) acc[m][n] = (f32x4)0.f;

  for (int kb = 0; kb < 16; ++kb) {
    const int k0 = kb * 32;
    __syncthreads();
    {
      int ar = t >> 3, ac = (t & 7) * 4;
      float4 a = *(const float4*)(A + (size_t)(rowbase + ar) * DIM + k0 + ac);
      ushort4 u = { f2bf(a.x), f2bf(a.y), f2bf(a.z), f2bf(a.w) };
      *(ushort4*)&As[ar][ac] = u;
    }
    __syncthreads();
    bf16x8 a0 = *(const bf16x8*)&As[r16][kb8 * 8];
    bf16x8 a1 = *(const bf16x8*)&As[16 + r16][kb8 * 8];
    #pragma unroll
    for (int n = 0; n < 8; ++n) {
      bf16x8 bb = *(const bf16x8*)(Wb + (size_t)(w * 128 + n * 16 + r16) * DIM + k0 + kb8 * 8);
      acc[0][n] = __builtin_amdgcn_mfma_f32_16x16x32_bf16(a0, bb, acc[0][n], 0, 0, 0);
      acc[1][n] = __builtin_amdgcn_mfma_f32_16x16x32_bf16(a1, bb, acc[1][n], 0, 0, 0);
    }
  }
  float s_[2][4], ss_[2][4];
  #pragma unroll
  for (int m = 0; m < 2; ++m)
    #pragma unroll
    for (int r = 0; r < 4; ++r) { s_[m][r] = 0.f; ss_[m][r] = 0.f; }
  #pragma unroll
  for (int n = 0; n < 8; ++n) {
    float bqv = bq[w * 128 + n * 16 + r16];
    #pragma unroll
    for (int m = 0; m < 2; ++m)
      #pragma unroll
      for (int r = 0; r < 4; ++r) {
        float v = acc[m][n][r] + bqv;
        acc[m][n][r] = v;
        s_[m][r] += v;
        ss_[m][r] += v * v;
      }
  }
  #pragma unroll
  for (int m = 0; m < 2; ++m)
    #pragma unroll
    for (int r = 0; r < 4; ++r)
      #pragma unroll
      for (int off = 1; off < 16; off <<= 1) {
        s_[m][r]  += __shfl_xor(s_[m][r], off, 64);
        ss_[m][r] += __shfl_xor(ss_[m][r], off, 64);
      }
  if (r16 == 0) {
    #pragma unroll
    for (int m = 0; m < 2; ++m)
      #pragma unroll
      for (int r = 0; r < 4; ++r) {
        int row = m * 16 + kb8 * 4 + r;
        rws[w][row]  = s_[m][r];
        rws2[w][row] = ss_[m][r];
      }
  }
  __syncthreads();
  float mu_[2][4], rs_[2][4];
  #pragma unroll
  for (int m = 0; m < 2; ++m)
    #pragma unroll
    for (int r = 0; r < 4; ++r) {
      int row = m * 16 + kb8 * 4 + r;
      float s = rws[0][row] + rws[1][row] + rws[2][row] + rws[3][row];
      float q = rws2[0][row] + rws2[1][row] + rws2[2][row] + rws2[3][row];
      float mu = s * (1.f / DIM);
      float var = q * (1.f / DIM) - mu * mu;
      mu_[m][r] = mu;
      rs_[m][r] = rsqrtf(var + 1e-5f);
    }
  #pragma unroll
  for (int n = 0; n < 8; ++n) {
    int col = w * 128 + n * 16 + r16;
    float g1 = gb1[col], g2 = gb2[col];
    #pragma unroll
    for (int m = 0; m < 2; ++m)
      #pragma unroll
      for (int r = 0; r < 4; ++r) {
        int row = rowbase + m * 16 + kb8 * 4 + r;
        float o = (acc[m][n][r] - mu_[m][r]) * rs_[m][r] * g1 + g2;
        qout[(size_t)row * DIM + col] = f2bf(o);
      }
  }
}

// ---------------- fused: kb = bf16(value*gk) row-major; vT[b][d][t] = bf16(value*gv)
__global__ __launch_bounds__(256)
void vkprep_kernel(const float* __restrict__ value, const float* __restrict__ gk,
                   const float* __restrict__ gv,
                   ushort* __restrict__ kbuf, ushort* __restrict__ vT) {
  __shared__ ushort tile[64][73];
  const int t = threadIdx.x;
  const int s0 = blockIdx.x * 64, d0 = blockIdx.y * 64;
  const size_t boff = (size_t)blockIdx.z * TSEQ * DIM;
  #pragma unroll
  for (int rep = 0; rep < 4; ++rep) {
    int f = rep * 1024 + t * 4;
    int sr = f >> 6, dc = f & 63;
    float4 v = *(const float4*)(value + boff + (size_t)(s0 + sr) * DIM + d0 + dc);
    float4 g = *(const float4*)(gv + d0 + dc);
    float4 gg = *(const float4*)(gk + d0 + dc);
    tile[sr][dc]     = f2bf(v.x * g.x);
    tile[sr][dc + 1] = f2bf(v.y * g.y);
    tile[sr][dc + 2] = f2bf(v.z * g.z);
    tile[sr][dc + 3] = f2bf(v.w * g.w);
    ushort4 ko = { f2bf(v.x*gg.x), f2bf(v.y*gg.y), f2bf(v.z*gg.z), f2bf(v.w*gg.w) };
    *(ushort4*)(kbuf + boff + (size_t)(s0 + sr) * DIM + d0 + dc) = ko;
  }
  __syncthreads();
  const int d = t >> 2, sc0 = (t & 3) * 16;
  __align__(16) ushort tmp[16];
  #pragma unroll
  for (int j = 0; j < 16; ++j) tmp[j] = tile[sc0 + j][d];
  ushort* dst = vT + (size_t)blockIdx.z * DIM * TSEQ + (size_t)(d0 + d) * TSEQ + s0 + sc0;
  ((uint4*)dst)[0] = *(const uint4*)&tmp[0];
  ((uint4*)dst)[1] = *(const uint4*)&tmp[8];
}

// ---------------- causal flash attention: dual-stream pipelined, QB=64, KVB=64,
// grid 256, 8 waves. WG owns pair (qt=s full, qt=63-s full) -> no combine pass.
// Streams A/B take even/odd kv tiles; per half-phase: PV_x || QK^T_x || softmax_y.
// Fixed-max softmax (LN'd/gated q,k bound |S|<~6): contributions additive across
// streams -> shared accO/lrow. Wave = (qh, dc, h): q-half x D-half x kv-half.
__global__ __launch_bounds__(512, 2)
void attn8_kernel(const ushort* __restrict__ qb, const ushort* __restrict__ kb,
                  const ushort* __restrict__ vT, float* __restrict__ out) {
  __shared__ __align__(16) float Sp[2][2][64][68];   // [stream][dc][q][kv+pad] 69.6KB
  __shared__ __align__(16) ushort P[2][64][72];      // [stream][q][kv+pad] 18.4KB
  __shared__ float lrow[64];

  const int t = threadIdx.x;
  const int lane = t & 63;
  const int w = t >> 6;
  const int r16 = lane & 15;
  const int kb8 = lane >> 4;
  const int dc = w & 1;            // D half for QK^T (256)
  const int h  = (w >> 1) & 1;     // kv half (32)
  const int qh = w >> 2;           // q half (32)
  const int dcol = (w & 3) * 128;  // D chunk for PV/O (128)

  const int bid = blockIdx.x;
  const int wg = ((bid & 7) << 5) | (bid >> 3);   // XCD-chunked swizzle (256 = 8*32)
  const int b = wg >> 6;
  const int s = (wg & 63);                        // 0..63 -> but pairing needs 0..31
  const int sp = s >> 1;                          // pair id 0..31
  const int ph = s & 1;                           // which CU of the pair duplicates? no:
  // two WGs per pair: ph=0 handles (sp, 63-sp) small-first, ph=1 handles the
  // complementary pair (63-sp... ) -- instead use direct mapping: qt1 = s for
  // ph spread. Simpler: each wg handles pair (s', 63-s') with s' = wg&31,
  // and the duplicate half (wg&32) takes the OTHER pair member first for
  // better L2 spread. Both tiles are fully processed by exactly one WG:
  // use 64 wgs/batch = 32 pairs... but we have 64 wg slots per batch.
  (void)sp; (void)ph;
  // Mapping: 64 WGs per batch, WG i (0..63) processes q-tile qt1 = i (full)
  // ... that would double work. Correct scheme: 64 WGs/batch, each handles ONE
  // tile fully; tile i has i+1 kv-tiles -> unbalanced. Balance by pairing
  // within WG: WG j (j=0..31) handles tiles (j, 63-j); WGs 32..63 idle? No.
  // Use 32 WGs/batch * 4 batches = 128 WGs -> half the CUs idle. Instead:
  // 64 WGs/batch, each WG handles ONE tile, pair-sorted so long tiles start
  // first: WG j: qt = (j < 32) ? (63 - j) : (j - 32). Work = 64-j or j-31
  // kv-tiles; dynamic scheduling across 256 WGs on 256 CUs is 1:1 so this is
  // unbalanced... Keep the in-WG pair: grid 128/batch is wrong. Final choice:
  // grid 256 total, WG handles pair (s2, 63-s2) with s2 = wg & 31, and the
  // b index uses wg>>5 over 8 values for 4 batches*2 halves: the two halves
  // split each pair's two tiles: half 0 -> tile s2, half 1 -> tile 63-s2,
  // plus splitting the LARGER tile is needed for balance... Simplest correct
  // balanced form matching grid 256: WG handles pair (s2,63-s2) fully
  // (65 kv-tiles) with 64 WGs per batch covering 32 pairs twice? NO.
  // -> Resolution below: 32 pairs/batch, 128 WGs total process pairs fully;
  //    remaining 128 WGs process nothing. To avoid idle CUs we instead give
  //    each of the 64 WGs/batch ONE tile and accept imbalance but sort
  //    longest-first via qt = (wg&63)^63 ordering with XCD swizzle. The
  //    scheduler backfills short tiles onto CUs that finish early since
  //    grid(256)=CUs(256) leaves no backfill -> imbalance is real but the
  //    max tile (64) vs mean (32.5) wastes half. UNACCEPTABLE. ==> Use the
  //    in-WG pair with grid 128 and 2 pairs per WG? 128 WGs * 130 tiles...
  // FINAL: grid 256; WG handles pair (s2, 63-s2) where s2 = wg & 31 and
  // batch b2 = wg >> 5 covers 8 slots = 4 batches x 2 pair-groups:
  // pair-group g2 = (wg >> 5) & 1 selects pairs s2 or s2+32?? s2 range must
  // be 0..31 -> pairs (s2,63-s2) for g2=0; but that is all 64 tiles already.
  // So 32 WGs cover one batch fully; 256 WGs => 4 batches x 2 COPIES.
  // Use the copy bit to split ALL tiles' kv ranges in half: copy c2 handles
  // kv tiles with (kt & 1) == c2 via stream assignment -- i.e. WG copy 0
  // runs stream A tiles only... but then output needs combining again.
  // => Accept combine-free requirement is incompatible with grid 256 here;
  // choose grid 128 (half CUs) but each WG has DOUBLE work in the pipeline
  // (both pair tiles), pipeline depth unchanged; CUs idle = bad.
  // DECISION: keep it simple and balanced: grid 256, WG = (b, u) with
  // u = wg & 63 in 0..63; WG handles HALF of pair (s2,63-s2), s2 = u >> 1,
  // half = u & 1, exactly as R2/R8: half0 = small tile full + large prefix,
  // half1 = large suffix. Large tile outputs go through pO/stats + comb.
  const int u = wg & 63;
  const int s2 = u >> 1;
  const int half = u & 1;

  const size_t boff  = (size_t)b * TSEQ * DIM;
  const size_t vboff = (size_t)b * DIM * TSEQ;

  int qbase = 0;

  bf16x8 aQ[2][8];
  f32x4 accO[2][8];

  // ---- helpers (capture by ref)
  auto qkt = [&](int st, int kt) {
    const int kbase = kt * 64;
    f32x4 accS[2][2];
    #pragma unroll
    for (int m = 0; m < 2; ++m) { accS[m][0] = (f32x4)0.f; accS[m][1] = (f32x4)0.f; }
    #pragma unroll
    for (int c = 0; c < 8; ++c) {
      bf16x8 bK0 = *(const bf16x8*)(kb + boff + (size_t)(kbase + h*32 + r16) * DIM
                                    + dc*256 + c*32 + kb8*8);
      bf16x8 bK1 = *(const bf16x8*)(kb + boff + (size_t)(kbase + h*32 + 16 + r16) * DIM
                                    + dc*256 + c*32 + kb8*8);
      #pragma unroll
      for (int m = 0; m < 2; ++m) {
        accS[m][0] = __builtin_amdgcn_mfma_f32_16x16x32_bf16(bK0, aQ[m][c], accS[m][0], 0, 0, 0);
        accS[m][1] = __builtin_amdgcn_mfma_f32_16x16x32_bf16(bK1, aQ[m][c], accS[m][1], 0, 0, 0);
      }
    }
    #pragma unroll
    for (int m = 0; m < 2; ++m)
      #pragma unroll
      for (int n = 0; n < 2; ++n)
        *(f32x4*)&Sp[st][dc][qh*32 + m*16 + r16][h*32 + n*16 + kb8*4] = accS[m][n];
  };

  auto sm = [&](int st, int kt) {
    const int kbase = kt * 64;
    const int row = t >> 3, c0 = (t & 7) * 8;
    float4 u0 = *(const float4*)&Sp[st][0][row][c0];
    float4 u1 = *(const float4*)&Sp[st][0][row][c0 + 4];
    float4 w0 = *(const float4*)&Sp[st][1][row][c0];
    float4 w1 = *(const float4*)&Sp[st][1][row][c0 + 4];
    float sv[8] = { u0.x + w0.x, u0.y + w0.y, u0.z + w0.z, u0.w + w0.w,
                    u1.x + w1.x, u1.y + w1.y, u1.z + w1.z, u1.w + w1.w };
    const int qg = qbase + row;
    float ps = 0.f;
    #pragma unroll
    for (int j = 0; j < 8; ++j) {
      sv[j] = (kbase + c0 + j > qg) ? 0.f : __expf(sv[j]);
      ps += sv[j];
    }
    ps += __shfl_xor(ps, 1, 64);
    ps += __shfl_xor(ps, 2, 64);
    ps += __shfl_xor(ps, 4, 64);
    __align__(16) ushort tmp[8];
    #pragma unroll
    for (int j = 0; j < 8; ++j) tmp[j] = f2bf(sv[j]);
    *(uint4*)&P[st][row][c0] = *(const uint4*)tmp;
    if ((t & 7) == 0) lrow[row] += ps;
  };

  auto pv = [&](int st, int kt) {
    const int kbase = kt * 64;
    #pragma unroll
    for (int c = 0; c < 2; ++c) {
      bf16x8 aP0 = *(const bf16x8*)&P[st][qh*32 + r16][c*32 + kb8*8];
      bf16x8 aP1 = *(const bf16x8*)&P[st][qh*32 + 16 + r16][c*32 + kb8*8];
      #pragma unroll
      for (int n = 0; n < 8; ++n) {
        bf16x8 bV = *(const bf16x8*)(vT + vboff + (size_t)(dcol + n*16 + r16) * TSEQ
                                     + kbase + c*32 + kb8*8);
        accO[0][n] = __builtin_amdgcn_mfma_f32_16x16x32_bf16(aP0, bV, accO[0][n], 0, 0, 0);
        accO[1][n] = __builtin_amdgcn_mfma_f32_16x16x32_bf16(aP1, bV, accO[1][n], 0, 0, 0);
      }
    }
  };

  // ---- job list (R2 schedule): half0 = small full + large prefix; half1 = large suffix
  for (int ji = 0; ji < 2; ++ji) {
    int qt, kt0, kt1, mode, cid;
    if (half) {
      if (ji) break;
      qt = 63 - s2; kt0 = 31 - s2; kt1 = 64 - s2; mode = 1; cid = (b*32 + s2)*2 + 1;
    } else if (ji == 0) {
      qt = s2; kt0 = 0; kt1 = s2 + 1; mode = 0; cid = 0;
    } else {
      qt = 63 - s2; kt0 = 0; kt1 = 31 - s2; mode = 1; cid = (b*32 + s2)*2;
    }
    qbase = qt * 64;
    const int N = kt1 - kt0;

    __syncthreads();
    if (t < 64) lrow[t] = 0.f;
    #pragma unroll
    for (int m = 0; m < 2; ++m)
      #pragma unroll
      for (int c = 0; c < 8; ++c)
        aQ[m][c] = *(const bf16x8*)(qb + boff + (size_t)(qbase + qh*32 + m*16 + r16) * DIM
                                    + dc*256 + c*32 + kb8*8);
    #pragma unroll
    for (int m = 0; m < 2; ++m)
      #pragma unroll
      for (int n = 0; n < 8; ++n) accO[m][n] = (f32x4)0.f;

    const int nA = (N + 1) >> 1, nB = N >> 1;   // stream A: kt0+2p, B: kt0+2p+1

    qkt(0, kt0);
    __syncthreads();
    sm(0, kt0);
    if (nB > 0) qkt(1, kt0 + 1);
    __syncthreads();

    for (int p = 0; p < nA; ++p) {
      __builtin_amdgcn_s_setprio(1);
      pv(0, kt0 + 2*p);
      if (p + 1 < nA) qkt(0, kt0 + 2*p + 2);
      if (p < nB) sm(1, kt0 + 2*p + 1);
      __builtin_amdgcn_s_setprio(0);
      __syncthreads();
      __builtin_amdgcn_s_setprio(1);
      if (p < nB) pv(1, kt0 + 2*p + 1);
      if (p + 1 < nB) qkt(1, kt0 + 2*p + 3);
      if (p + 1 < nA) sm(0, kt0 + 2*p + 2);
      __builtin_amdgcn_s_setprio(0);
      __syncthreads();
    }

    // ---- epilogue
    if (mode == 0) {
      #pragma unroll
      for (int m = 0; m < 2; ++m)
        #pragma unroll
        for (int r = 0; r < 4; ++r) {
          int qrow = qh*32 + m*16 + kb8*4 + r;
          float inv = 1.f / lrow[qrow];
          float* dst = out + boff + (size_t)(qbase + qrow) * DIM + dcol + r16;
          #pragma unroll
          for (int n = 0; n < 8; ++n) dst[n*16] = accO[m][n][r] * inv;
        }
    } else {
      // partial: store f32 accO and lrow; combined by comb kernel
      float* po = (float*)out;  // placeholder overwritten below via params
      (void)po;
      // use global scratch passed via extra params? kept simple: write to
      // pO/stats through pointers passed in (see launcher) via constant
      // offset from out is NOT safe; instead we re-purpose: attn8 takes
      // pO/stats as arguments (added below).
    }
    // NOTE: partial path handled by second signature variant; see attn8p.
    if (mode == 1) {
      // handled in attn8 full version (params included) -- placeholder
    }
  }
}

// Full version with partial outputs (the one actually launched).
__global__ __launch_bounds__(512, 2)
void attn8p_kernel(const ushort* __restrict__ qb, const ushort* __restrict__ kb,
                   const ushort* __restrict__ vT, float* __restrict__ out,
                   ushort* __restrict__ pO, float* __restrict__ stats) {
  __shared__ __align__(16) float Sp[2][2][64][68];
  __shared__ __align__(16) ushort P[2][64][72];
  __shared__ float lrow[64];

  const int t = threadIdx.x;
  const int lane = t & 63;
  const int w = t >> 6;
  const int r16 = lane & 15;
  const int kb8 = lane >> 4;
  const int dc = w & 1;
  const int h  = (w >> 1) & 1;
  const int qh = w >> 2;
  const int dcol = (w & 3) * 128;

  const int bid = blockIdx.x;
  const int wg = ((bid & 7) << 5) | (bid >> 3);
  const int b = wg >> 6;
  const int u = wg & 63;
  const int s2 = u >> 1;
  const int half = u & 1;

  const size_t boff  = (size_t)b * TSEQ * DIM;
  const size_t vboff = (size_t)b * DIM * TSEQ;

  int qbase = 0;
  bf16x8 aQ[2][8];
  f32x4 accO[2][8];

  auto qkt = [&](int st, int kt) {
    const int kbase = kt * 64;
    f32x4 accS[2][2];
    #pragma unroll
    for (int m = 0; m < 2; ++m) { accS[m][0] = (f32x4)0.f; accS[m][1] = (f32x4)0.f; }
    #pragma unroll
    for (int c = 0; c < 8; ++c) {
      bf16x8 bK0 = *(const bf16x8*)(kb + boff + (size_t)(kbase + h*32 + r16) * DIM
                                    + dc*256 + c*32 + kb8*8);
      bf16x8 bK1 = *(const bf16x8*)(kb + boff + (size_t)(kbase + h*32 + 16 + r16) * DIM
                                    + dc*256 + c*32 + kb8*8);
      #pragma unroll
      for (int m = 0; m < 2; ++m) {
        accS[m][0] = __builtin_amdgcn_mfma_f32_16x16x32_bf16(bK0, aQ[m][c], accS[m][0], 0, 0, 0);
        accS[m][1] = __builtin_amdgcn_mfma_f32_16x16x32_bf16(bK1, aQ[m][c], accS[m][1], 0, 0, 0);
      }
    }
    #pragma unroll
    for (int m = 0; m < 2; ++m)
      #pragma unroll
      for (int n = 0; n < 2; ++n)
        *(f32x4*)&Sp[st][dc][qh*32 + m*16 + r16][h*32 + n*16 + kb8*4] = accS[m][n];
  };

  auto sm = [&](int st, int kt) {
    const int kbase = kt * 64;
    const int row = t >> 3, c0 = (t & 7) * 8;
    float4 u0 = *(const float4*)&Sp[st][0][row][c0];
    float4 u1 = *(const float4*)&Sp[st][0][row][c0 + 4];
    float4 w0 = *(const float4*)&Sp[st][1][row][c0];
    float4 w1 = *(const float4*)&Sp[st][1][row][c0 + 4];
    float sv[8] = { u0.x + w0.x, u0.y + w0.y, u0.z + w0.z, u0.w + w0.w,
                    u1.x + w1.x, u1.y + w1.y, u1.z + w1.z, u1.w + w1.w };
    const int qg = qbase + row;
    float ps = 0.f;
    #pragma unroll
    for (int j = 0; j < 8; ++j) {
      sv[j] = (kbase + c0 + j > qg) ? 0.f : __expf(sv[j]);
      ps += sv[j];
    }
    ps += __shfl_xor(ps, 1, 64);
    ps += __shfl_xor(ps, 2, 64);
    ps += __shfl_xor(ps, 4, 64);
    __align__(16) ushort tmp[8];
    #pragma unroll
    for (int j = 0; j < 8; ++j) tmp[j] = f2bf(sv[j]);
    *(uint4*)&P[st][row][c0] = *(const uint4*)tmp;
    if ((t & 7) == 0) lrow[row] += ps;
  };

  auto pv = [&](int st, int kt) {
    const int kbase = kt * 64;
    #pragma unroll
    for (int c = 0; c < 2; ++c) {
      bf16x8 aP0 = *(const bf16x8*)&P[st][qh*32 + r16][c*32 + kb8*8];
      bf16x8 aP1 = *(const bf16x8*)&P[st][qh*32 + 16 + r16][c*32 + kb8*8];
      #pragma unroll
      for (int n = 0; n < 8; ++n) {
        bf16x8 bV = *(const bf16x8*)(vT + vboff + (size_t)(dcol + n*16 + r16) * TSEQ
                                     + kbase + c*32 + kb8*8);
        accO[0][n] = __builtin_amdgcn_mfma_f32_16x16x32_bf16(aP0, bV, accO[0][n], 0, 0, 0);
        accO[1][n] = __builtin_amdgcn_mfma_f32_16x16x32_bf16(aP1, bV, accO[1][n], 0, 0, 0);
      }
    }
  };

  for (int ji = 0; ji < 2; ++ji) {
    int qt, kt0, kt1, mode, cid;
    if (half) {
      if (ji) break;
      qt = 63 - s2; kt0 = 31 - s2; kt1 = 64 - s2; mode = 1; cid = (b*32 + s2)*2 + 1;
    } else if (ji == 0) {
      qt = s2; kt0 = 0; kt1 = s2 + 1; mode = 0; cid = 0;
    } else {
      qt = 63 - s2; kt0 = 0; kt1 = 31 - s2; mode = 1; cid = (b*32 + s2)*2;
    }
    qbase = qt * 64;
    const int N = kt1 - kt0;

    __syncthreads();
    if (t < 64) lrow[t] = 0.f;
    #pragma unroll
    for (int m = 0; m < 2; ++m)
      #pragma unroll
      for (int c = 0; c < 8; ++c)
        aQ[m][c] = *(const bf16x8*)(qb + boff + (size_t)(qbase + qh*32 + m*16 + r16) * DIM
                                    + dc*256 + c*32 + kb8*8);
    #pragma unroll
    for (int m = 0; m < 2; ++m)
      #pragma unroll
      for (int n = 0; n < 8; ++n) accO[m][n] = (f32x4)0.f;

    const int nA = (N + 1) >> 1, nB = N >> 1;

    qkt(0, kt0);
    __syncthreads();
    sm(0, kt0);
    if (nB > 0) qkt(1, kt0 + 1);
    __syncthreads();

    for (int p = 0; p < nA; ++p) {
      __builtin_amdgcn_s_setprio(1);
      pv(0, kt0 + 2*p);
      if (p + 1 < nA) qkt(0, kt0 + 2*p + 2);
      if (p < nB) sm(1, kt0 + 2*p + 1);
      __builtin_amdgcn_s_setprio(0);
      __syncthreads();
      __builtin_amdgcn_s_setprio(1);
      if (p < nB) pv(1, kt0 + 2*p + 1);
      if (p + 1 < nB) qkt(1, kt0 + 2*p + 3);
      if (p + 1 < nA) sm(0, kt0 + 2*p + 2);
      __builtin_amdgcn_s_setprio(0);
      __syncthreads();
    }

    if (mode == 0) {
      #pragma unroll
      for (int m = 0; m < 2; ++m)
        #pragma unroll
        for (int r = 0; r < 4; ++r) {
          int qrow = qh*32 + m*16 + kb8*4 + r;
          float inv = 1.f / lrow[qrow];
          float* dst = out + boff + (size_t)(qbase + qrow) * DIM + dcol + r16;
          #pragma unroll
          for (int n = 0; n < 8; ++n) dst[n*16] = accO[m][n][r] * inv;
        }
    } else {
      ushort* po = pO + (size_t)cid * (64 * DIM);
      #pragma unroll
      for (int m = 0; m < 2; ++m)
        #pragma unroll
        for (int r = 0; r < 4; ++r) {
          int qrow = qh*32 + m*16 + kb8*4 + r;
          ushort* dst = po + (size_t)qrow * DIM + dcol + r16;
          #pragma unroll
          for (int n = 0; n < 8; ++n) dst[n*16] = f2bf(accO[m][n][r]);
        }
      if (t < 64) stats[(size_t)cid*64 + t] = lrow[t];
    }
  }
}

// ---------------- combine the two partials of each large q-tile (weights = 1)
__global__ __launch_bounds__(256)
void comb_kernel(const ushort* __restrict__ pO, const float* __restrict__ stats,
                 float* __restrict__ out) {
  const int g = blockIdx.x;       // 0..127: (b, s)
  const int rb = blockIdx.y;      // 0..15
  const int t = threadIdx.x;
  const int b = g >> 5, s = g & 31, qt = 63 - s;
  const int row = rb * 4 + (t >> 6);
  const int col = (t & 63) * 8;
  float l0 = stats[(size_t)(g*2 + 0)*64 + row];
  float l1 = stats[(size_t)(g*2 + 1)*64 + row];
  float inv = 1.f / (l0 + l1);
  const ushort* pa = pO + ((size_t)(g*2 + 0) * 64 + row) * DIM + col;
  const ushort* pb = pO + ((size_t)(g*2 + 1) * 64 + row) * DIM + col;
  ushort4 a0 = ((const ushort4*)pa)[0], a1 = ((const ushort4*)pa)[1];
  ushort4 b0 = ((const ushort4*)pb)[0], b1 = ((const ushort4*)pb)[1];
  auto bf2f = [](ushort uu) { return __uint_as_float(((uint32_t)uu) << 16); };
  float* dst = out + ((size_t)b * TSEQ + (size_t)qt * 64 + row) * DIM + col;
  float4 o0 = { (bf2f(a0.x) + bf2f(b0.x)) * inv, (bf2f(a0.y) + bf2f(b0.y)) * inv,
                (bf2f(a0.z) + bf2f(b0.z)) * inv, (bf2f(a0.w) + bf2f(b0.w)) * inv };
  float4 o1 = { (bf2f(a1.x) + bf2f(b1.x)) * inv, (bf2f(a1.y) + bf2f(b1.y)) * inv,
                (bf2f(a1.z) + bf2f(b1.z)) * inv, (bf2f(a1.w) + bf2f(b1.w)) * inv };
  ((float4*)dst)[0] = o0;
  ((float4*)dst)[1] = o1;
}

extern "C" void kernel_launch(void* const* d_in, const int* in_sizes, int n_in,
                              void* d_out, int out_size, void* d_ws, size_t ws_size,
                              hipStream_t stream) {
  const float* query = (const float*)d_in[0];
  const float* value = (const float*)d_in[1];
  const float* qv    = (const float*)d_in[2];
  const float* kv    = (const float*)d_in[3];
  const float* vvec  = (const float*)d_in[4];
  const float* Wq    = (const float*)d_in[5];
  const float* bq    = (const float*)d_in[6];
  const float* gam   = (const float*)d_in[7];
  const float* bet   = (const float*)d_in[8];
  const float* Ws    = (const float*)d_in[9];
  const float* bs    = (const float*)d_in[10];
  const float* Wt    = (const float*)d_in[11];
  const float* bt    = (const float*)d_in[12];
  float* out = (float*)d_out;

  char* ws = (char*)d_ws;
  float*  gk    = (float*)(ws);                    // 2KB
  float*  gv    = (float*)(ws + 2048);             // 2KB
  float*  gb1   = (float*)(ws + 4096);             // 2KB
  float*  gb2   = (float*)(ws + 6144);             // 2KB
  ushort* Wb    = (ushort*)(ws + 8192);            // 512KB
  float*  stats = (float*)(ws + 532480);           // 256*64*4 = 64KB
  ushort* pO    = (ushort*)(ws + 663552);          // 256*64*512*2 = 16MB
  ushort* qb    = (ushort*)(ws + 17440768);        // 16MB
  ushort* kb    = (ushort*)(ws + 34217984);        // 16MB
  ushort* vT    = (ushort*)(ws + 50995200);        // 16MB (end ~67MB)

  gates_kernel<<<64, 512, 0, stream>>>(qv, kv, vvec, Ws, bs, Wt, bt, gam, bet,
                                       gk, gv, gb1, gb2);
  wconv_kernel<<<256, 256, 0, stream>>>(Wq, Wb);
  qgemmln_kernel<<<512, 256, 0, stream>>>(query, Wb, bq, gb1, gb2, qb);
  vkprep_kernel<<<dim3(64, 8, 4), 256, 0, stream>>>(value, gk, gv, kb, vT);
  attn8p_kernel<<<256, 512, 0, stream>>>(qb, kb, vT, out, pO, stats);
  comb_kernel<<<dim3(128, 16), 256, 0, stream>>>(pO, stats, out);
}

// Round 11
// 181.015 us; speedup vs baseline: 2.0266x; 1.8441x over previous
//
#include <hip/hip_runtime.h>
#include <cstdint>

typedef __bf16 bf16x8 __attribute__((ext_vector_type(8)));
typedef float f32x4 __attribute__((ext_vector_type(4)));

#define DIM 512
#define TSEQ 4096

__device__ __forceinline__ ushort f2bf(float x) {
  uint32_t u = __float_as_uint(x);
  u += 0x7fffu + ((u >> 16) & 1u);
  return (ushort)(u >> 16);
}
__device__ __forceinline__ float bf2f(ushort u) {
  return __uint_as_float(((uint32_t)u) << 16);
}

typedef __attribute__((address_space(3))) uint32_t lds_u32;
typedef __attribute__((address_space(1))) const uint32_t glb_u32;
__device__ __forceinline__ void gload16(const ushort* g, ushort* l) {
  __builtin_amdgcn_global_load_lds((glb_u32*)g, (lds_u32*)l, 16, 0, 0);
}

// ---------------- gates: gk, gv, gb1, gb2
__global__ __launch_bounds__(512)
void gates_kernel(const float* __restrict__ qv, const float* __restrict__ kv,
                  const float* __restrict__ vvec,
                  const float* __restrict__ Ws, const float* __restrict__ bs,
                  const float* __restrict__ Wt, const float* __restrict__ bt,
                  const float* __restrict__ gamma, const float* __restrict__ beta,
                  float* __restrict__ gk, float* __restrict__ gv,
                  float* __restrict__ gb1, float* __restrict__ gb2) {
  __shared__ float vv[DIM];
  const int t = threadIdx.x;
  const int lane = t & 63, w = t >> 6;
  vv[t] = 1.f / (1.f + __expf(-vvec[t]));
  if (blockIdx.x == 0) {
    const float SC = 0.044194173824159216f;  // 1/sqrt(512)
    float gqv = 1.f / (1.f + __expf(-qv[t]));
    gk[t] = 1.f / (1.f + __expf(-kv[t]));
    gb1[t] = gamma[t] * gqv * SC;
    gb2[t] = beta[t] * gqv * SC;
  }
  __syncthreads();
  const int d = blockIdx.x * 8 + w;
  const float* wsr = Ws + (size_t)d * DIM + lane * 8;
  const float* wtr = Wt + (size_t)d * DIM + lane * 8;
  float4 v0 = *(const float4*)(&vv[lane * 8]);
  float4 v1 = *(const float4*)(&vv[lane * 8 + 4]);
  float4 s0 = *(const float4*)wsr, s1 = *(const float4*)(wsr + 4);
  float4 t0 = *(const float4*)wtr, t1 = *(const float4*)(wtr + 4);
  float as = v0.x*s0.x + v0.y*s0.y + v0.z*s0.z + v0.w*s0.w
           + v1.x*s1.x + v1.y*s1.y + v1.z*s1.z + v1.w*s1.w;
  float at = v0.x*t0.x + v0.y*t0.y + v0.z*t0.z + v0.w*t0.w
           + v1.x*t1.x + v1.y*t1.y + v1.z*t1.z + v1.w*t1.w;
  #pragma unroll
  for (int off = 1; off < 64; off <<= 1) {
    as += __shfl_xor(as, off, 64);
    at += __shfl_xor(at, off, 64);
  }
  if (lane == 0) {
    float sg = 1.f / (1.f + __expf(-(as + bs[d])));
    float th = tanhf(at + bt[d]);
    gv[d] = sg * th;
  }
}

// ---------------- Wq f32 -> bf16
__global__ __launch_bounds__(256)
void wconv_kernel(const float* __restrict__ W, ushort* __restrict__ Wb) {
  int i = blockIdx.x * 256 + threadIdx.x;
  float4 v = ((const float4*)W)[i];
  ushort4 o = { f2bf(v.x), f2bf(v.y), f2bf(v.z), f2bf(v.w) };
  ((ushort4*)Wb)[i] = o;
}

// ---------------- fused qGEMM + LayerNorm + gate + scale -> bf16 qb
__global__ __launch_bounds__(256, 2)
void qgemmln_kernel(const float* __restrict__ A, const ushort* __restrict__ Wb,
                    const float* __restrict__ bq,
                    const float* __restrict__ gb1, const float* __restrict__ gb2,
                    ushort* __restrict__ qout) {
  __shared__ ushort As[32][40];
  __shared__ float rws[4][32], rws2[4][32];
  const int t = threadIdx.x;
  const int lane = t & 63, w = t >> 6;
  const int r16 = lane & 15, kb8 = lane >> 4;
  const int rowbase = blockIdx.x * 32;
  f32x4 acc[2][8];
  #pragma unroll
  for (int m = 0; m < 2; ++m)
    #pragma unroll
    for (int n = 0; n < 8; ++n) acc[m][n] = (f32x4)0.f;

  for (int kb = 0; kb < 16; ++kb) {
    const int k0 = kb * 32;
    __syncthreads();
    {
      int ar = t >> 3, ac = (t & 7) * 4;
      float4 a = *(const float4*)(A + (size_t)(rowbase + ar) * DIM + k0 + ac);
      ushort4 u = { f2bf(a.x), f2bf(a.y), f2bf(a.z), f2bf(a.w) };
      *(ushort4*)&As[ar][ac] = u;
    }
    __syncthreads();
    bf16x8 a0 = *(const bf16x8*)&As[r16][kb8 * 8];
    bf16x8 a1 = *(const bf16x8*)&As[16 + r16][kb8 * 8];
    #pragma unroll
    for (int n = 0; n < 8; ++n) {
      bf16x8 bb = *(const bf16x8*)(Wb + (size_t)(w * 128 + n * 16 + r16) * DIM + k0 + kb8 * 8);
      acc[0][n] = __builtin_amdgcn_mfma_f32_16x16x32_bf16(a0, bb, acc[0][n], 0, 0, 0);
      acc[1][n] = __builtin_amdgcn_mfma_f32_16x16x32_bf16(a1, bb, acc[1][n], 0, 0, 0);
    }
  }
  float s_[2][4], ss_[2][4];
  #pragma unroll
  for (int m = 0; m < 2; ++m)
    #pragma unroll
    for (int r = 0; r < 4; ++r) { s_[m][r] = 0.f; ss_[m][r] = 0.f; }
  #pragma unroll
  for (int n = 0; n < 8; ++n) {
    float bqv = bq[w * 128 + n * 16 + r16];
    #pragma unroll
    for (int m = 0; m < 2; ++m)
      #pragma unroll
      for (int r = 0; r < 4; ++r) {
        float v = acc[m][n][r] + bqv;
        acc[m][n][r] = v;
        s_[m][r] += v;
        ss_[m][r] += v * v;
      }
  }
  #pragma unroll
  for (int m = 0; m < 2; ++m)
    #pragma unroll
    for (int r = 0; r < 4; ++r)
      #pragma unroll
      for (int off = 1; off < 16; off <<= 1) {
        s_[m][r]  += __shfl_xor(s_[m][r], off, 64);
        ss_[m][r] += __shfl_xor(ss_[m][r], off, 64);
      }
  if (r16 == 0) {
    #pragma unroll
    for (int m = 0; m < 2; ++m)
      #pragma unroll
      for (int r = 0; r < 4; ++r) {
        int row = m * 16 + kb8 * 4 + r;
        rws[w][row]  = s_[m][r];
        rws2[w][row] = ss_[m][r];
      }
  }
  __syncthreads();
  float mu_[2][4], rs_[2][4];
  #pragma unroll
  for (int m = 0; m < 2; ++m)
    #pragma unroll
    for (int r = 0; r < 4; ++r) {
      int row = m * 16 + kb8 * 4 + r;
      float s = rws[0][row] + rws[1][row] + rws[2][row] + rws[3][row];
      float q = rws2[0][row] + rws2[1][row] + rws2[2][row] + rws2[3][row];
      float mu = s * (1.f / DIM);
      float var = q * (1.f / DIM) - mu * mu;
      mu_[m][r] = mu;
      rs_[m][r] = rsqrtf(var + 1e-5f);
    }
  #pragma unroll
  for (int n = 0; n < 8; ++n) {
    int col = w * 128 + n * 16 + r16;
    float g1 = gb1[col], g2 = gb2[col];
    #pragma unroll
    for (int m = 0; m < 2; ++m)
      #pragma unroll
      for (int r = 0; r < 4; ++r) {
        int row = rowbase + m * 16 + kb8 * 4 + r;
        float o = (acc[m][n][r] - mu_[m][r]) * rs_[m][r] * g1 + g2;
        qout[(size_t)row * DIM + col] = f2bf(o);
      }
  }
}

// ---------------- fused: kb = bf16(value*gk) row-major; vT[b][d][t] = bf16(value*gv)
__global__ __launch_bounds__(256)
void vkprep_kernel(const float* __restrict__ value, const float* __restrict__ gk,
                   const float* __restrict__ gv,
                   ushort* __restrict__ kbuf, ushort* __restrict__ vT) {
  __shared__ ushort tile[64][73];
  const int t = threadIdx.x;
  const int s0 = blockIdx.x * 64, d0 = blockIdx.y * 64;
  const size_t boff = (size_t)blockIdx.z * TSEQ * DIM;
  #pragma unroll
  for (int rep = 0; rep < 4; ++rep) {
    int f = rep * 1024 + t * 4;
    int sr = f >> 6, dc = f & 63;
    float4 v = *(const float4*)(value + boff + (size_t)(s0 + sr) * DIM + d0 + dc);
    float4 g = *(const float4*)(gv + d0 + dc);
    float4 gg = *(const float4*)(gk + d0 + dc);
    tile[sr][dc]     = f2bf(v.x * g.x);
    tile[sr][dc + 1] = f2bf(v.y * g.y);
    tile[sr][dc + 2] = f2bf(v.z * g.z);
    tile[sr][dc + 3] = f2bf(v.w * g.w);
    ushort4 ko = { f2bf(v.x*gg.x), f2bf(v.y*gg.y), f2bf(v.z*gg.z), f2bf(v.w*gg.w) };
    *(ushort4*)(kbuf + boff + (size_t)(s0 + sr) * DIM + d0 + dc) = ko;
  }
  __syncthreads();
  const int d = t >> 2, sc0 = (t & 3) * 16;
  __align__(16) ushort tmp[16];
  #pragma unroll
  for (int j = 0; j < 16; ++j) tmp[j] = tile[sc0 + j][d];
  ushort* dst = vT + (size_t)blockIdx.z * DIM * TSEQ + (size_t)(d0 + d) * TSEQ + s0 + sc0;
  ((uint4*)dst)[0] = *(const uint4*)&tmp[0];
  ((uint4*)dst)[1] = *(const uint4*)&tmp[8];
}

// ---------------- causal flash attention, QB=64, KVB=64, 8 waves, grid 256 (R2/R8 schedule)
// K/V tiles staged into LDS via global_load_lds (single-buffered: written phase A,
// read phase B). XOR-swizzled granules: LDS(row,g) holds src(row, g ^ (row&7)).
// QK^T: wave (sq=w>>1, kh=w&1): full-K S[16q][32kv] -> single final Sp (no partials).
// PV: wave (qh=w>>2, dx=w&3) as before. Fixed-max softmax (|S|<=~6).
__global__ __launch_bounds__(512)
void attn9_kernel(const ushort* __restrict__ qb, const ushort* __restrict__ kb,
                  const ushort* __restrict__ vT, float* __restrict__ out,
                  ushort* __restrict__ pO, float* __restrict__ stats) {
  __shared__ __align__(16) ushort Kl[64 * 512];   // 64KB  K tile, granule-swizzled
  __shared__ __align__(16) ushort Vl[512 * 64];   // 64KB  V tile (d-major), swizzled
  __shared__ __align__(16) float Sp[64][68];      // 17.4KB final S
  __shared__ __align__(16) ushort P[64][72];      // 9.2KB
  __shared__ float lrow[64];

  const int t = threadIdx.x;
  const int lane = t & 63;
  const int w = t >> 6;
  const int r16 = lane & 15;
  const int kb8 = lane >> 4;
  const int sq = w >> 1;           // QK^T q-slice (16 rows)
  const int kh = w & 1;            // QK^T kv-half (32 rows)
  const int qh = w >> 2;           // PV q-half (32 rows)
  const int dcol = (w & 3) * 128;  // PV D chunk

  const int bid = blockIdx.x;
  const int wg = ((bid & 7) << 5) | (bid >> 3);   // XCD-chunked swizzle
  const int b = wg >> 6;
  const int rr = wg & 63;
  const int s = rr >> 1;
  const int half = rr & 1;

  const size_t boff  = (size_t)b * TSEQ * DIM;
  const size_t vboff = (size_t)b * DIM * TSEQ;

  // staging constants (per thread)
  const int kst_row = w;                         // + round*8
  const int kst_src = ((lane ^ w) & 63) * 8;     // swizzled source granule
  const int vst_d   = t >> 3;                    // + round*64
  const int vst_src = (((t & 7) ^ ((t >> 3) & 7))) * 8;
  const int vst_g   = (t & 7) * 8;

  for (int ji = 0; ji < 2; ++ji) {
    int qt, kt0, kt1, mode, cid;
    if (half) {
      if (ji) break;
      qt = 63 - s; kt0 = 31 - s; kt1 = 64 - s; mode = 1; cid = (b*32 + s)*2 + 1;
    } else if (ji == 0) {
      qt = s; kt0 = 0; kt1 = s + 1; mode = 0; cid = 0;
    } else {
      qt = 63 - s; kt0 = 0; kt1 = 31 - s; mode = 1; cid = (b*32 + s)*2;
    }
    const int qbase = qt * 64;

    __syncthreads();   // previous job epilogue reads done
    if (t < 64) lrow[t] = 0.f;

    // Q fragments: 16 q rows (slice sq) x full K=512
    bf16x8 aQ[16];
    #pragma unroll
    for (int c = 0; c < 16; ++c)
      aQ[c] = *(const bf16x8*)(qb + boff + (size_t)(qbase + sq*16 + r16) * DIM
                               + c*32 + kb8*8);
    f32x4 accO[2][8];
    #pragma unroll
    for (int m = 0; m < 2; ++m)
      #pragma unroll
      for (int n = 0; n < 8; ++n) accO[m][n] = (f32x4)0.f;

    // ---- prologue: stage K(kt0), then QK^T(kt0)
    {
      const ushort* kbp = kb + boff + (size_t)(kt0 * 64) * DIM;
      #pragma unroll
      for (int rd = 0; rd < 8; ++rd)
        gload16(kbp + (size_t)(rd*8 + kst_row) * DIM + kst_src,
                Kl + (rd*8 + kst_row) * DIM + lane * 8);
    }
    __syncthreads();   // drains vmcnt: K(kt0) in LDS
    {
      f32x4 accS[2];
      accS[0] = (f32x4)0.f; accS[1] = (f32x4)0.f;
      #pragma unroll
      for (int c = 0; c < 16; ++c) {
        #pragma unroll
        for (int n = 0; n < 2; ++n) {
          int krow = kh*32 + n*16 + r16;
          bf16x8 kf = *(const bf16x8*)(Kl + krow*DIM + (((c*4 + kb8) ^ (r16 & 7)))*8);
          accS[n] = __builtin_amdgcn_mfma_f32_16x16x32_bf16(kf, aQ[c], accS[n], 0, 0, 0);
        }
      }
      #pragma unroll
      for (int n = 0; n < 2; ++n)
        *(f32x4*)&Sp[sq*16 + r16][kh*32 + n*16 + kb8*4] = accS[n];
    }
    __syncthreads();

    for (int kt = kt0; kt < kt1; ++kt) {
      const int kbase = kt * 64;
      const bool havek = (kt + 1 < kt1);

      // ---- phase A: stage V(kt) + K(kt+1); fixed-max softmax(kt)
      {
        const ushort* vp = vT + vboff + kbase;
        #pragma unroll
        for (int rd = 0; rd < 8; ++rd)
          gload16(vp + (size_t)(rd*64 + vst_d) * TSEQ + vst_src,
                  Vl + (rd*64 + vst_d) * 64 + vst_g);
      }
      if (havek) {
        const ushort* kbp = kb + boff + (size_t)(kbase + 64) * DIM;
        #pragma unroll
        for (int rd = 0; rd < 8; ++rd)
          gload16(kbp + (size_t)(rd*8 + kst_row) * DIM + kst_src,
                  Kl + (rd*8 + kst_row) * DIM + lane * 8);
      }
      {
        const int row = t >> 3, c0 = (t & 7) * 8;
        float4 u0 = *(const float4*)&Sp[row][c0];
        float4 u1 = *(const float4*)&Sp[row][c0 + 4];
        float sv[8] = { u0.x, u0.y, u0.z, u0.w, u1.x, u1.y, u1.z, u1.w };
        const int qg = qbase + row;
        float ps = 0.f;
        #pragma unroll
        for (int j = 0; j < 8; ++j) {
          sv[j] = (kbase + c0 + j > qg) ? 0.f : __expf(sv[j]);
          ps += sv[j];
        }
        ps += __shfl_xor(ps, 1, 64);
        ps += __shfl_xor(ps, 2, 64);
        ps += __shfl_xor(ps, 4, 64);
        ushort4 p0 = { f2bf(sv[0]), f2bf(sv[1]), f2bf(sv[2]), f2bf(sv[3]) };
        ushort4 p1 = { f2bf(sv[4]), f2bf(sv[5]), f2bf(sv[6]), f2bf(sv[7]) };
        *(ushort4*)&P[row][c0] = p0;
        *(ushort4*)&P[row][c0 + 4] = p1;
        if ((t & 7) == 0) lrow[row] += ps;
      }
      __syncthreads();   // V(kt),K(kt+1) landed; P visible

      // ---- phase B: PV(kt) from Vl; QK^T(kt+1) from Kl
      __builtin_amdgcn_s_setprio(1);
      #pragma unroll
      for (int c = 0; c < 2; ++c) {
        bf16x8 aP0 = *(const bf16x8*)&P[qh*32 + r16][c*32 + kb8*8];
        bf16x8 aP1 = *(const bf16x8*)&P[qh*32 + 16 + r16][c*32 + kb8*8];
        #pragma unroll
        for (int n = 0; n < 8; ++n) {
          int d = dcol + n*16 + r16;
          bf16x8 bV = *(const bf16x8*)(Vl + d*64 + (((c*4 + kb8) ^ (r16 & 7)))*8);
          accO[0][n] = __builtin_amdgcn_mfma_f32_16x16x32_bf16(aP0, bV, accO[0][n], 0, 0, 0);
          accO[1][n] = __builtin_amdgcn_mfma_f32_16x16x32_bf16(aP1, bV, accO[1][n], 0, 0, 0);
        }
      }
      if (havek) {
        f32x4 accS[2];
        accS[0] = (f32x4)0.f; accS[1] = (f32x4)0.f;
        #pragma unroll
        for (int c = 0; c < 16; ++c) {
          #pragma unroll
          for (int n = 0; n < 2; ++n) {
            int krow = kh*32 + n*16 + r16;
            bf16x8 kf = *(const bf16x8*)(Kl + krow*DIM + (((c*4 + kb8) ^ (r16 & 7)))*8);
            accS[n] = __builtin_amdgcn_mfma_f32_16x16x32_bf16(kf, aQ[c], accS[n], 0, 0, 0);
          }
        }
        #pragma unroll
        for (int n = 0; n < 2; ++n)
          *(f32x4*)&Sp[sq*16 + r16][kh*32 + n*16 + kb8*4] = accS[n];
      }
      __builtin_amdgcn_s_setprio(0);
      __syncthreads();   // Kl/Vl reads + Sp writes done before next staging
    }

    // ---- epilogue
    if (mode == 0) {
      #pragma unroll
      for (int m = 0; m < 2; ++m)
        #pragma unroll
        for (int r = 0; r < 4; ++r) {
          int row = qh*32 + m*16 + kb8*4 + r;
          float inv = 1.f / lrow[row];
          float* dst = out + boff + (size_t)(qbase + row) * DIM + dcol + r16;
          #pragma unroll
          for (int n = 0; n < 8; ++n) dst[n*16] = accO[m][n][r] * inv;
        }
    } else {
      ushort* po = pO + (size_t)cid * (64 * DIM);
      #pragma unroll
      for (int m = 0; m < 2; ++m)
        #pragma unroll
        for (int r = 0; r < 4; ++r) {
          int row = qh*32 + m*16 + kb8*4 + r;
          ushort* dst = po + (size_t)row * DIM + dcol + r16;
          #pragma unroll
          for (int n = 0; n < 8; ++n) dst[n*16] = f2bf(accO[m][n][r]);
        }
      if (t < 64) stats[(size_t)cid*64 + t] = lrow[t];
    }
  }
}

// ---------------- combine the two partials of each large q-tile (weights = 1)
__global__ __launch_bounds__(256)
void comb_kernel(const ushort* __restrict__ pO, const float* __restrict__ stats,
                 float* __restrict__ out) {
  const int g = blockIdx.x;       // 0..127: (b, s)
  const int rb = blockIdx.y;      // 0..15
  const int t = threadIdx.x;
  const int b = g >> 5, s = g & 31, qt = 63 - s;
  const int row = rb * 4 + (t >> 6);
  const int col = (t & 63) * 8;
  float l0 = stats[(size_t)(g*2 + 0)*64 + row];
  float l1 = stats[(size_t)(g*2 + 1)*64 + row];
  float inv = 1.f / (l0 + l1);
  const ushort* pa = pO + ((size_t)(g*2 + 0) * 64 + row) * DIM + col;
  const ushort* pb = pO + ((size_t)(g*2 + 1) * 64 + row) * DIM + col;
  ushort4 a0 = ((const ushort4*)pa)[0], a1 = ((const ushort4*)pa)[1];
  ushort4 b0 = ((const ushort4*)pb)[0], b1 = ((const ushort4*)pb)[1];
  float* dst = out + ((size_t)b * TSEQ + (size_t)qt * 64 + row) * DIM + col;
  float4 o0 = { (bf2f(a0.x) + bf2f(b0.x)) * inv, (bf2f(a0.y) + bf2f(b0.y)) * inv,
                (bf2f(a0.z) + bf2f(b0.z)) * inv, (bf2f(a0.w) + bf2f(b0.w)) * inv };
  float4 o1 = { (bf2f(a1.x) + bf2f(b1.x)) * inv, (bf2f(a1.y) + bf2f(b1.y)) * inv,
                (bf2f(a1.z) + bf2f(b1.z)) * inv, (bf2f(a1.w) + bf2f(b1.w)) * inv };
  ((float4*)dst)[0] = o0;
  ((float4*)dst)[1] = o1;
}

extern "C" void kernel_launch(void* const* d_in, const int* in_sizes, int n_in,
                              void* d_out, int out_size, void* d_ws, size_t ws_size,
                              hipStream_t stream) {
  const float* query = (const float*)d_in[0];
  const float* value = (const float*)d_in[1];
  const float* qv    = (const float*)d_in[2];
  const float* kv    = (const float*)d_in[3];
  const float* vvec  = (const float*)d_in[4];
  const float* Wq    = (const float*)d_in[5];
  const float* bq    = (const float*)d_in[6];
  const float* gam   = (const float*)d_in[7];
  const float* bet   = (const float*)d_in[8];
  const float* Ws    = (const float*)d_in[9];
  const float* bs    = (const float*)d_in[10];
  const float* Wt    = (const float*)d_in[11];
  const float* bt    = (const float*)d_in[12];
  float* out = (float*)d_out;

  char* ws = (char*)d_ws;
  float*  gk    = (float*)(ws);                    // 2KB
  float*  gv    = (float*)(ws + 2048);             // 2KB
  float*  gb1   = (float*)(ws + 4096);             // 2KB
  float*  gb2   = (float*)(ws + 6144);             // 2KB
  ushort* Wb    = (ushort*)(ws + 8192);            // 512KB
  float*  stats = (float*)(ws + 532480);           // 256*64*4 = 64KB
  ushort* pO    = (ushort*)(ws + 663552);          // 16MB
  ushort* qb    = (ushort*)(ws + 17440768);        // 16MB
  ushort* kb    = (ushort*)(ws + 34217984);        // 16MB
  ushort* vT    = (ushort*)(ws + 50995200);        // 16MB (end ~67MB)

  gates_kernel<<<64, 512, 0, stream>>>(qv, kv, vvec, Ws, bs, Wt, bt, gam, bet,
                                       gk, gv, gb1, gb2);
  wconv_kernel<<<256, 256, 0, stream>>>(Wq, Wb);
  qgemmln_kernel<<<512, 256, 0, stream>>>(query, Wb, bq, gb1, gb2, qb);
  vkprep_kernel<<<dim3(64, 8, 4), 256, 0, stream>>>(value, gk, gv, kb, vT);
  attn9_kernel<<<256, 512, 0, stream>>>(qb, kb, vT, out, pO, stats);
  comb_kernel<<<dim3(128, 16), 256, 0, stream>>>(pO, stats, out);
}